// Round 4
// baseline (879.636 us; speedup 1.0000x reference)
//
#include <hip/hip_runtime.h>
#include <hip/hip_bf16.h>
#include <math.h>

typedef __attribute__((ext_vector_type(8))) short short8;
typedef __attribute__((ext_vector_type(4))) float f32x4;

__device__ __forceinline__ unsigned short f2bf(float x) {
    __hip_bfloat16 b = __float2bfloat16(x);
    return *reinterpret_cast<unsigned short*>(&b);
}
__device__ __forceinline__ float gelu_exact(float x) {
    return 0.5f * x * (1.0f + erff(x * 0.70710678118654752f));
}

// ---------------------------------------------------------------- zero (ws-too-small diagnostic)
__global__ __launch_bounds__(256) void k_zero(float* __restrict__ p, long n)
{
    long i = (long)blockIdx.x * 256 + threadIdx.x;
    if (i < n) p[i] = 0.f;
}

// ---------------------------------------------------------------- layernorm (fp32 -> fp32)
// one wave per 64-wide row; 4 rows per block
__global__ __launch_bounds__(256) void k_layernorm(
    const float* __restrict__ x, const float* __restrict__ g,
    const float* __restrict__ b, float* __restrict__ out)
{
    int wave = threadIdx.x >> 6, lane = threadIdx.x & 63;
    long row = (long)blockIdx.x * 4 + wave;
    float v = x[row * 64 + lane];
    float s = v;
    #pragma unroll
    for (int o = 32; o; o >>= 1) s += __shfl_xor(s, o);
    float m = s * (1.0f / 64.0f);
    float d = v - m;
    float q = d * d;
    #pragma unroll
    for (int o = 32; o; o >>= 1) q += __shfl_xor(q, o);
    float rstd = rsqrtf(q * (1.0f / 64.0f) + 1e-5f);
    out[row * 64 + lane] = d * rstd * g[lane] + b[lane];
}

// ---------------------------------------------------------------- Wfold = Wqkv_v @ Wout  [64,64]
__global__ __launch_bounds__(256) void k_wfold(
    const float* __restrict__ Wqkv, const float* __restrict__ Wout,
    float* __restrict__ Wfold)
{
    int idx = blockIdx.x * 256 + threadIdx.x;   // 4096 outputs
    int c = idx >> 6, d = idx & 63;
    float a = 0.f;
    for (int k = 0; k < 256; ++k)
        a += Wqkv[c * 768 + 512 + k] * Wout[k * 64 + d];
    Wfold[idx] = a;
}

// ---------------------------------------------------------------- q,k gemm (batch 0 only)
// q|k[4096,256] (bf16) = xn[0:4096,64] @ Wqkv[:, 0:512]
__global__ __launch_bounds__(256) void k_qk(
    const float* __restrict__ xn, const float* __restrict__ W,
    unsigned short* __restrict__ q, unsigned short* __restrict__ kmat)
{
    __shared__ float As[64][65];
    __shared__ float Ws[64][65];
    int tid = threadIdx.x;
    int m0 = blockIdx.x * 64, n0 = blockIdx.y * 64;
    #pragma unroll
    for (int it = 0; it < 16; ++it) {
        int idx = tid + it * 256;
        int r = idx >> 6, c = idx & 63;
        As[r][c] = xn[(long)(m0 + r) * 64 + c];
        Ws[r][c] = W[(long)r * 768 + n0 + c];
    }
    __syncthreads();
    int tx = tid & 15, ty = tid >> 4;
    float acc[4][4] = {};
    #pragma unroll
    for (int k = 0; k < 64; ++k) {
        float a[4], w[4];
        #pragma unroll
        for (int i = 0; i < 4; ++i) a[i] = As[ty * 4 + i][k];
        #pragma unroll
        for (int j = 0; j < 4; ++j) w[j] = Ws[k][tx * 4 + j];
        #pragma unroll
        for (int i = 0; i < 4; ++i)
            #pragma unroll
            for (int j = 0; j < 4; ++j) acc[i][j] += a[i] * w[j];
    }
    #pragma unroll
    for (int i = 0; i < 4; ++i) {
        long row = m0 + ty * 4 + i;
        #pragma unroll
        for (int j = 0; j < 4; ++j) {
            int col = n0 + tx * 4 + j;
            if (col < 256) q[row * 256 + col] = f2bf(acc[i][j]);
            else           kmat[row * 256 + (col - 256)] = f2bf(acc[i][j]);
        }
    }
}

// ---------------------------------------------------------------- vWT = (xn @ Wfold)^T packed
// vWT[b*64+d][n] = sum_c xn[b*4096+n][c] * Wfold[c][d]   -> [128, 4096] bf16
__global__ __launch_bounds__(256) void k_xnw_t(
    const float* __restrict__ xn, const float* __restrict__ Wfold,
    unsigned short* __restrict__ vWT)
{
    __shared__ float As[64][65];
    __shared__ float Ws[64][65];
    int tid = threadIdx.x;
    int n0 = blockIdx.x * 64, b = blockIdx.y;
    #pragma unroll
    for (int it = 0; it < 16; ++it) {
        int idx = tid + it * 256;
        int r = idx >> 6, c = idx & 63;
        As[r][c] = xn[((long)b * 4096 + n0 + r) * 64 + c];
        Ws[r][c] = Wfold[r * 64 + c];
    }
    __syncthreads();
    int tx = tid & 15, ty = tid >> 4;
    float acc[4][4] = {};
    #pragma unroll
    for (int k = 0; k < 64; ++k) {
        float a[4], w[4];
        #pragma unroll
        for (int i = 0; i < 4; ++i) a[i] = As[ty * 4 + i][k];
        #pragma unroll
        for (int j = 0; j < 4; ++j) w[j] = Ws[k][tx * 4 + j];
        #pragma unroll
        for (int i = 0; i < 4; ++i)
            #pragma unroll
            for (int j = 0; j < 4; ++j) acc[i][j] += a[i] * w[j];
    }
    #pragma unroll
    for (int i = 0; i < 4; ++i)
        #pragma unroll
        for (int j = 0; j < 4; ++j)
            vWT[((long)b * 64 + tx * 4 + j) * 4096 + n0 + ty * 4 + i] = f2bf(acc[i][j]);
}

// ---------------------------------------------------------------- MFMA NT gemm
// C[M,N] fp32 = scale * A[M,K] @ B[N,K]^T ; B bf16 row-major (K contig);
// A bf16 (a_f32=0) or fp32 converted during staging (a_f32=1).
// 128x128 tile, BK=64, 4 waves of 64x64, 16x16x32 bf16 MFMA
__global__ __launch_bounds__(256) void k_mfma_nt(
    const void* __restrict__ Ap, const unsigned short* __restrict__ B,
    float* __restrict__ C, int N, int K, float scale, int a_f32)
{
    __shared__ __align__(16) unsigned short As[128 * 64];
    __shared__ __align__(16) unsigned short Bs[128 * 64];
    int tid = threadIdx.x;
    int lane = tid & 63, wave = tid >> 6;
    long m0 = (long)blockIdx.x * 128, n0 = (long)blockIdx.y * 128;
    const unsigned short* Bg = B + n0 * K;
    int wm = (wave & 1) * 64, wn = (wave >> 1) * 64;
    int fr = lane & 15, quad = lane >> 4;

    f32x4 acc[4][4];
    #pragma unroll
    for (int i = 0; i < 4; ++i)
        #pragma unroll
        for (int j = 0; j < 4; ++j) acc[i][j] = (f32x4){0.f, 0.f, 0.f, 0.f};

    for (int k0 = 0; k0 < K; k0 += 64) {
        #pragma unroll
        for (int it = 0; it < 4; ++it) {
            int c = tid + it * 256;        // 8-elem chunk, 1024 chunks per tile
            int r = c >> 3, col = (c & 7) * 8;
            if (a_f32) {
                const float* Ag = (const float*)Ap + m0 * K;
                float4 f0 = *(const float4*)(Ag + (long)r * K + k0 + col);
                float4 f1 = *(const float4*)(Ag + (long)r * K + k0 + col + 4);
                short8 s;
                s[0] = (short)f2bf(f0.x); s[1] = (short)f2bf(f0.y);
                s[2] = (short)f2bf(f0.z); s[3] = (short)f2bf(f0.w);
                s[4] = (short)f2bf(f1.x); s[5] = (short)f2bf(f1.y);
                s[6] = (short)f2bf(f1.z); s[7] = (short)f2bf(f1.w);
                *(short8*)&As[c * 8] = s;
            } else {
                const unsigned short* Ag = (const unsigned short*)Ap + m0 * K;
                *(short8*)&As[c * 8] = *(const short8*)(Ag + (long)r * K + k0 + col);
            }
            *(short8*)&Bs[c * 8] = *(const short8*)(Bg + (long)r * K + k0 + col);
        }
        __syncthreads();
        #pragma unroll
        for (int ks = 0; ks < 2; ++ks) {
            short8 af[4], bfr[4];
            #pragma unroll
            for (int i = 0; i < 4; ++i) {
                af[i]  = *(const short8*)&As[(wm + i * 16 + fr) * 64 + ks * 32 + quad * 8];
                bfr[i] = *(const short8*)&Bs[(wn + i * 16 + fr) * 64 + ks * 32 + quad * 8];
            }
            #pragma unroll
            for (int i = 0; i < 4; ++i)
                #pragma unroll
                for (int j = 0; j < 4; ++j)
                    acc[i][j] = __builtin_amdgcn_mfma_f32_16x16x32_bf16(
                        af[i], bfr[j], acc[i][j], 0, 0, 0);
        }
        __syncthreads();
    }
    #pragma unroll
    for (int i = 0; i < 4; ++i) {
        #pragma unroll
        for (int j = 0; j < 4; ++j) {
            long col = n0 + wn + j * 16 + fr;
            long rowb = m0 + wm + i * 16 + quad * 4;
            #pragma unroll
            for (int r = 0; r < 4; ++r)
                C[(rowb + r) * N + col] = acc[i][j][r] * scale;
        }
    }
}

// ---------------------------------------------------------------- block reduce helpers
__device__ __forceinline__ float block_max(float v, float* red, int lane, int wave) {
    #pragma unroll
    for (int o = 32; o; o >>= 1) v = fmaxf(v, __shfl_xor(v, o));
    if (lane == 0) red[wave] = v;
    __syncthreads();
    v = fmaxf(fmaxf(red[0], red[1]), fmaxf(red[2], red[3]));
    __syncthreads();
    return v;
}
__device__ __forceinline__ float block_sum(float v, float* red, int lane, int wave) {
    #pragma unroll
    for (int o = 32; o; o >>= 1) v += __shfl_xor(v, o);
    if (lane == 0) red[wave] = v;
    __syncthreads();
    v = red[0] + red[1] + red[2] + red[3];
    __syncthreads();
    return v;
}

// ---------------------------------------------------------------- masked softmax -> attn (fp32)
// e = where(A>0, dots, -inf); e[diag]=1.0 (AFTER mask); attn = softmax(e)
__global__ __launch_bounds__(256) void k_softmax_attn(
    const float* __restrict__ dots, const float* __restrict__ Aadj,
    float* __restrict__ attn_out)
{
    __shared__ float red[4];
    int row = blockIdx.x, tid = threadIdx.x;
    int lane = tid & 63, wave = tid >> 6;
    const float* drow = dots + (long)row * 4096;
    const float* arow = Aadj + (long)row * 4096;
    float mv[16];
    float mmax = -1e30f;
    #pragma unroll
    for (int i = 0; i < 16; ++i) {
        int j = tid + i * 256;
        float m = (arow[j] > 0.f) ? drow[j] : -1e30f;
        if (j == row) m = 1.0f;
        mv[i] = m;
        mmax = fmaxf(mmax, m);
    }
    float M1 = block_max(mmax, red, lane, wave);
    float s1 = 0.f;
    #pragma unroll
    for (int i = 0; i < 16; ++i) { float e = expf(mv[i] - M1); mv[i] = e; s1 += e; }
    s1 = block_sum(s1, red, lane, wave);
    float inv1 = 1.0f / s1;
    #pragma unroll
    for (int i = 0; i < 16; ++i)
        attn_out[(long)row * 4096 + tid + i * 256] = mv[i] * inv1;
}

// ---------------------------------------------------------------- unmasked softmax, IN PLACE (fp32)
// run LAST: ds <- softmax(ds) row-wise. block==row; all reads precede writes.
__global__ __launch_bounds__(256) void k_softmax_ds(float* ds)
{
    __shared__ float red[4];
    int row = blockIdx.x, tid = threadIdx.x;
    int lane = tid & 63, wave = tid >> 6;
    float* drow = ds + (long)row * 4096;
    float d[16];
    float umax = -1e30f;
    #pragma unroll
    for (int i = 0; i < 16; ++i) {
        d[i] = drow[tid + i * 256];
        umax = fmaxf(umax, d[i]);
    }
    float M = block_max(umax, red, lane, wave);
    float s = 0.f;
    #pragma unroll
    for (int i = 0; i < 16; ++i) { float e = expf(d[i] - M); d[i] = e; s += e; }
    s = block_sum(s, red, lane, wave);
    float inv = 1.0f / s;
    #pragma unroll
    for (int i = 0; i < 16; ++i)
        drow[tid + i * 256] = d[i] * inv;
}

// ---------------------------------------------------------------- x = xn + avcat(reindex) + bout
__global__ __launch_bounds__(256) void k_avres(
    const float* __restrict__ xn, const float* __restrict__ avcat,
    const float* __restrict__ bout, float* __restrict__ x)
{
    int idx = blockIdx.x * 256 + threadIdx.x;   // 524288
    int r = idx >> 6, c = idx & 63;
    int b = r >> 12, n = r & 4095;
    x[idx] = xn[idx] + avcat[(long)n * 128 + b * 64 + c] + bout[c];
}

// ---------------------------------------------------------------- MLP gemm, K=64, N=64 (fp32)
// out[M,64] = act(A[M,64] @ W[64,64] + bias) (+ res)
__global__ __launch_bounds__(256) void k_gemm64(
    const float* __restrict__ A, const float* __restrict__ W,
    const float* __restrict__ bias, const float* __restrict__ res,
    float* __restrict__ out, int act)
{
    __shared__ float As[64][65];
    __shared__ float Ws[64][65];
    int tid = threadIdx.x;
    int m0 = blockIdx.x * 64;
    #pragma unroll
    for (int it = 0; it < 16; ++it) {
        int idx = tid + it * 256;
        int r = idx >> 6, c = idx & 63;
        As[r][c] = A[(long)(m0 + r) * 64 + c];
        Ws[r][c] = W[(long)r * 64 + c];
    }
    __syncthreads();
    int tx = tid & 15, ty = tid >> 4;
    float acc[4][4] = {};
    #pragma unroll
    for (int k = 0; k < 64; ++k) {
        float a[4], w[4];
        #pragma unroll
        for (int i = 0; i < 4; ++i) a[i] = As[ty * 4 + i][k];
        #pragma unroll
        for (int j = 0; j < 4; ++j) w[j] = Ws[k][tx * 4 + j];
        #pragma unroll
        for (int i = 0; i < 4; ++i)
            #pragma unroll
            for (int j = 0; j < 4; ++j) acc[i][j] += a[i] * w[j];
    }
    #pragma unroll
    for (int i = 0; i < 4; ++i) {
        long row = m0 + ty * 4 + i;
        #pragma unroll
        for (int j = 0; j < 4; ++j) {
            int col = tx * 4 + j;
            float v = acc[i][j] + bias[col];
            if (act) v = gelu_exact(v);
            if (res) v += res[row * 64 + col];
            out[row * 64 + col] = v;
        }
    }
}

// ---------------------------------------------------------------- launch
extern "C" void kernel_launch(void* const* d_in, const int* in_sizes, int n_in,
                              void* d_out, int out_size, void* d_ws, size_t ws_size,
                              hipStream_t stream)
{
    const float* embed = (const float*)d_in[0];
    const float* Aadj  = (const float*)d_in[1];
    const float* g1    = (const float*)d_in[2];
    const float* b1    = (const float*)d_in[3];
    const float* Wqkv  = (const float*)d_in[4];
    const float* Wout  = (const float*)d_in[5];
    const float* bout  = (const float*)d_in[6];
    const float* g2    = (const float*)d_in[7];
    const float* b2    = (const float*)d_in[8];
    const float* W1    = (const float*)d_in[9];
    const float* bb1   = (const float*)d_in[10];
    const float* W2    = (const float*)d_in[11];
    const float* bb2   = (const float*)d_in[12];
    const float* gf    = (const float*)d_in[13];
    const float* bff   = (const float*)d_in[14];

    // output regions (fp32): [x 524288 | attn 16777216 | ds 16777216]
    float* ox    = (float*)d_out;            // final x; hosts avcat fp32 [4096,128] as scratch
    float* attnb = ox + 524288;              // [4096,4096] attn (fp32)
    float* dsb   = attnb + 16777216;         // [4096,4096] raw dots -> softmaxed in place LAST

    // diagnostic guard: if ws too small, zero output and bail (finite absmax => ws issue)
    if (ws_size < (10ull << 20)) {
        k_zero<<<133120, 256, 0, stream>>>(ox, 34078720l);
        return;
    }

    // workspace: 9.02 MB
    char* ws = (char*)d_ws;
    float*          x     = (float*)(ws + (0l << 20));            // 2 MB [8192,64]
    float*          xn    = (float*)(ws + (2l << 20));            // 2 MB xn / xm
    float*          h     = (float*)(ws + (4l << 20));            // 2 MB MLP hidden
    unsigned short* q     = (unsigned short*)(ws + (6l << 20));   // 1 MB [4096,256] bf16
    unsigned short* kmat  = (unsigned short*)(ws + (7l << 20));   // 1 MB [4096,256] bf16
    unsigned short* vwt   = (unsigned short*)(ws + (8l << 20));   // 1 MB [128,4096] bf16
    float*          Wfold = (float*)(ws + (9l << 20));            // 16 KB [64,64]

    for (int l = 0; l < 2; ++l) {
        const float* Wq = Wqkv + (long)l * 64 * 768;
        k_layernorm<<<2048, 256, 0, stream>>>(l ? x : embed, g1 + 64 * l, b1 + 64 * l, xn);
        k_wfold<<<16, 256, 0, stream>>>(Wq, Wout + (long)l * 256 * 64, Wfold);
        k_qk<<<dim3(64, 8), 256, 0, stream>>>(xn, Wq, q, kmat);
        k_xnw_t<<<dim3(64, 2), 256, 0, stream>>>(xn, Wfold, vwt);
        // dots = 0.125 * q @ k^T -> ds region (fp32)
        k_mfma_nt<<<dim3(32, 32), 256, 0, stream>>>(q, kmat, dsb, 4096, 256, 0.125f, 0);
        k_softmax_attn<<<4096, 256, 0, stream>>>(dsb, Aadj, attnb);
        // avcat[n][b*64+d] = attn @ vWT^T  (A fp32 converted in staging)
        k_mfma_nt<<<dim3(32, 1), 256, 0, stream>>>(attnb, vwt, ox, 128, 4096, 1.0f, 1);
        k_avres<<<2048, 256, 0, stream>>>(xn, ox, bout + 64 * l, x);
        k_layernorm<<<2048, 256, 0, stream>>>(x, g2 + 64 * l, b2 + 64 * l, xn);  // xm
        k_gemm64<<<128, 256, 0, stream>>>(xn, W1 + (long)l * 4096, bb1 + 64 * l,
                                          nullptr, h, 1);                 // h = gelu(...)
        k_gemm64<<<128, 256, 0, stream>>>(h, W2 + (long)l * 4096, bb2 + 64 * l,
                                          xn, x, 0);                      // x = xm + mlp
    }
    k_layernorm<<<2048, 256, 0, stream>>>(x, gf, bff, ox);   // final x (overwrites avcat)
    k_softmax_ds<<<4096, 256, 0, stream>>>(dsb);             // ds in place, LAST
}

// Round 5
// 520.337 us; speedup vs baseline: 1.6905x; 1.6905x over previous
//
#include <hip/hip_runtime.h>
#include <hip/hip_bf16.h>
#include <math.h>

typedef __attribute__((ext_vector_type(8))) short short8;
typedef __attribute__((ext_vector_type(4))) float f32x4;

__device__ __forceinline__ unsigned short f2bf(float x) {
    __hip_bfloat16 b = __float2bfloat16(x);
    return *reinterpret_cast<unsigned short*>(&b);
}
__device__ __forceinline__ float gelu_exact(float x) {
    return 0.5f * x * (1.0f + erff(x * 0.70710678118654752f));
}

// ---------------------------------------------------------------- zero
__global__ __launch_bounds__(256) void k_zero(float* __restrict__ p, long n)
{
    long i = (long)blockIdx.x * 256 + threadIdx.x;
    if (i < n) p[i] = 0.f;
}

// ---------------------------------------------------------------- layernorm (fp32 -> fp32)
__global__ __launch_bounds__(256) void k_layernorm(
    const float* __restrict__ x, const float* __restrict__ g,
    const float* __restrict__ b, float* __restrict__ out)
{
    int wave = threadIdx.x >> 6, lane = threadIdx.x & 63;
    long row = (long)blockIdx.x * 4 + wave;
    float v = x[row * 64 + lane];
    float s = v;
    #pragma unroll
    for (int o = 32; o; o >>= 1) s += __shfl_xor(s, o);
    float m = s * (1.0f / 64.0f);
    float d = v - m;
    float q = d * d;
    #pragma unroll
    for (int o = 32; o; o >>= 1) q += __shfl_xor(q, o);
    float rstd = rsqrtf(q * (1.0f / 64.0f) + 1e-5f);
    out[row * 64 + lane] = d * rstd * g[lane] + b[lane];
}

// ---------------------------------------------------------------- Wfold = Wqkv_v @ Wout  [64,64]
__global__ __launch_bounds__(256) void k_wfold(
    const float* __restrict__ Wqkv, const float* __restrict__ Wout,
    float* __restrict__ Wfold)
{
    int idx = blockIdx.x * 256 + threadIdx.x;   // 4096 outputs
    int c = idx >> 6, d = idx & 63;
    float a = 0.f;
    for (int k = 0; k < 256; ++k)
        a += Wqkv[c * 768 + 512 + k] * Wout[k * 64 + d];
    Wfold[idx] = a;
}

// ---------------------------------------------------------------- mask pack: bit j = A[row][j] > 0
__global__ __launch_bounds__(256) void k_maskpack(
    const float* __restrict__ Aadj, unsigned long long* __restrict__ mask)
{
    int row = blockIdx.x;
    int wave = threadIdx.x >> 6, lane = threadIdx.x & 63;
    for (int w = wave; w < 64; w += 4) {
        float a = Aadj[(long)row * 4096 + w * 64 + lane];
        unsigned long long m = __ballot(a > 0.f);
        if (lane == 0) mask[(long)row * 64 + w] = m;
    }
}

// ---------------------------------------------------------------- q,k gemm (batch 0 only)
__global__ __launch_bounds__(256) void k_qk(
    const float* __restrict__ xn, const float* __restrict__ W,
    unsigned short* __restrict__ q, unsigned short* __restrict__ kmat)
{
    __shared__ float As[64][65];
    __shared__ float Ws[64][65];
    int tid = threadIdx.x;
    int m0 = blockIdx.x * 64, n0 = blockIdx.y * 64;
    #pragma unroll
    for (int it = 0; it < 16; ++it) {
        int idx = tid + it * 256;
        int r = idx >> 6, c = idx & 63;
        As[r][c] = xn[(long)(m0 + r) * 64 + c];
        Ws[r][c] = W[(long)r * 768 + n0 + c];
    }
    __syncthreads();
    int tx = tid & 15, ty = tid >> 4;
    float acc[4][4] = {};
    #pragma unroll
    for (int k = 0; k < 64; ++k) {
        float a[4], w[4];
        #pragma unroll
        for (int i = 0; i < 4; ++i) a[i] = As[ty * 4 + i][k];
        #pragma unroll
        for (int j = 0; j < 4; ++j) w[j] = Ws[k][tx * 4 + j];
        #pragma unroll
        for (int i = 0; i < 4; ++i)
            #pragma unroll
            for (int j = 0; j < 4; ++j) acc[i][j] += a[i] * w[j];
    }
    #pragma unroll
    for (int i = 0; i < 4; ++i) {
        long row = m0 + ty * 4 + i;
        #pragma unroll
        for (int j = 0; j < 4; ++j) {
            int col = n0 + tx * 4 + j;
            if (col < 256) q[row * 256 + col] = f2bf(acc[i][j]);
            else           kmat[row * 256 + (col - 256)] = f2bf(acc[i][j]);
        }
    }
}

// ---------------------------------------------------------------- vWT = (xn @ Wfold)^T packed
// vWT[b*64+d][n]  -> [128, 4096] bf16
__global__ __launch_bounds__(256) void k_xnw_t(
    const float* __restrict__ xn, const float* __restrict__ Wfold,
    unsigned short* __restrict__ vWT)
{
    __shared__ float As[64][65];
    __shared__ float Ws[64][65];
    int tid = threadIdx.x;
    int n0 = blockIdx.x * 64, b = blockIdx.y;
    #pragma unroll
    for (int it = 0; it < 16; ++it) {
        int idx = tid + it * 256;
        int r = idx >> 6, c = idx & 63;
        As[r][c] = xn[((long)b * 4096 + n0 + r) * 64 + c];
        Ws[r][c] = Wfold[r * 64 + c];
    }
    __syncthreads();
    int tx = tid & 15, ty = tid >> 4;
    float acc[4][4] = {};
    #pragma unroll
    for (int k = 0; k < 64; ++k) {
        float a[4], w[4];
        #pragma unroll
        for (int i = 0; i < 4; ++i) a[i] = As[ty * 4 + i][k];
        #pragma unroll
        for (int j = 0; j < 4; ++j) w[j] = Ws[k][tx * 4 + j];
        #pragma unroll
        for (int i = 0; i < 4; ++i)
            #pragma unroll
            for (int j = 0; j < 4; ++j) acc[i][j] += a[i] * w[j];
    }
    #pragma unroll
    for (int i = 0; i < 4; ++i)
        #pragma unroll
        for (int j = 0; j < 4; ++j)
            vWT[((long)b * 64 + tx * 4 + j) * 4096 + n0 + ty * 4 + i] = f2bf(acc[i][j]);
}

// ---------------------------------------------------------------- dots GEMM (NT, bf16 in, fp32 out)
// C[M,N] = scale * A[M,K] @ B[N,K]^T ; 128x128 tile, BK=64
__global__ __launch_bounds__(256) void k_mfma_nt(
    const unsigned short* __restrict__ A, const unsigned short* __restrict__ B,
    float* __restrict__ C, int N, int K, float scale)
{
    __shared__ __align__(16) unsigned short As[128 * 64];
    __shared__ __align__(16) unsigned short Bs[128 * 64];
    int tid = threadIdx.x;
    int lane = tid & 63, wave = tid >> 6;
    long m0 = (long)blockIdx.x * 128, n0 = (long)blockIdx.y * 128;
    const unsigned short* Ag = A + m0 * K;
    const unsigned short* Bg = B + n0 * K;
    int wm = (wave & 1) * 64, wn = (wave >> 1) * 64;
    int fr = lane & 15, quad = lane >> 4;

    f32x4 acc[4][4];
    #pragma unroll
    for (int i = 0; i < 4; ++i)
        #pragma unroll
        for (int j = 0; j < 4; ++j) acc[i][j] = (f32x4){0.f, 0.f, 0.f, 0.f};

    for (int k0 = 0; k0 < K; k0 += 64) {
        #pragma unroll
        for (int it = 0; it < 4; ++it) {
            int c = tid + it * 256;
            int r = c >> 3, col = (c & 7) * 8;
            *(short8*)&As[c * 8] = *(const short8*)(Ag + (long)r * K + k0 + col);
            *(short8*)&Bs[c * 8] = *(const short8*)(Bg + (long)r * K + k0 + col);
        }
        __syncthreads();
        #pragma unroll
        for (int ks = 0; ks < 2; ++ks) {
            short8 af[4], bfr[4];
            #pragma unroll
            for (int i = 0; i < 4; ++i) {
                af[i]  = *(const short8*)&As[(wm + i * 16 + fr) * 64 + ks * 32 + quad * 8];
                bfr[i] = *(const short8*)&Bs[(wn + i * 16 + fr) * 64 + ks * 32 + quad * 8];
            }
            #pragma unroll
            for (int i = 0; i < 4; ++i)
                #pragma unroll
                for (int j = 0; j < 4; ++j)
                    acc[i][j] = __builtin_amdgcn_mfma_f32_16x16x32_bf16(
                        af[i], bfr[j], acc[i][j], 0, 0, 0);
        }
        __syncthreads();
    }
    #pragma unroll
    for (int i = 0; i < 4; ++i) {
        #pragma unroll
        for (int j = 0; j < 4; ++j) {
            long col = n0 + wn + j * 16 + fr;
            long rowb = m0 + wm + i * 16 + quad * 4;
            #pragma unroll
            for (int r = 0; r < 4; ++r)
                C[(rowb + r) * N + col] = acc[i][j][r] * scale;
        }
    }
}

// ---------------------------------------------------------------- attn@vWT split-K GEMM
// C[4096,128] += A[4096,4096](fp32, bf16-converted) @ B[128,4096]^T
// grid (32 m-tiles, 8 k-chunks of 512); accumulate via device-scope atomicAdd.
__global__ __launch_bounds__(256) void k_mfma_splitk(
    const float* __restrict__ A, const unsigned short* __restrict__ B,
    float* __restrict__ C)
{
    __shared__ __align__(16) unsigned short As[128 * 64];
    __shared__ __align__(16) unsigned short Bs[128 * 64];
    const int K = 4096, N = 128;
    int tid = threadIdx.x;
    int lane = tid & 63, wave = tid >> 6;
    long m0 = (long)blockIdx.x * 128;
    int k0base = blockIdx.y * 512;
    const float* Ag = A + m0 * K;
    int wm = (wave & 1) * 64, wn = (wave >> 1) * 64;
    int fr = lane & 15, quad = lane >> 4;

    f32x4 acc[4][4];
    #pragma unroll
    for (int i = 0; i < 4; ++i)
        #pragma unroll
        for (int j = 0; j < 4; ++j) acc[i][j] = (f32x4){0.f, 0.f, 0.f, 0.f};

    for (int k0 = k0base; k0 < k0base + 512; k0 += 64) {
        #pragma unroll
        for (int it = 0; it < 4; ++it) {
            int c = tid + it * 256;
            int r = c >> 3, col = (c & 7) * 8;
            float4 f0 = *(const float4*)(Ag + (long)r * K + k0 + col);
            float4 f1 = *(const float4*)(Ag + (long)r * K + k0 + col + 4);
            short8 s;
            s[0] = (short)f2bf(f0.x); s[1] = (short)f2bf(f0.y);
            s[2] = (short)f2bf(f0.z); s[3] = (short)f2bf(f0.w);
            s[4] = (short)f2bf(f1.x); s[5] = (short)f2bf(f1.y);
            s[6] = (short)f2bf(f1.z); s[7] = (short)f2bf(f1.w);
            *(short8*)&As[c * 8] = s;
            *(short8*)&Bs[c * 8] = *(const short8*)(B + (long)r * K + k0 + col);
        }
        __syncthreads();
        #pragma unroll
        for (int ks = 0; ks < 2; ++ks) {
            short8 af[4], bfr[4];
            #pragma unroll
            for (int i = 0; i < 4; ++i) {
                af[i]  = *(const short8*)&As[(wm + i * 16 + fr) * 64 + ks * 32 + quad * 8];
                bfr[i] = *(const short8*)&Bs[(wn + i * 16 + fr) * 64 + ks * 32 + quad * 8];
            }
            #pragma unroll
            for (int i = 0; i < 4; ++i)
                #pragma unroll
                for (int j = 0; j < 4; ++j)
                    acc[i][j] = __builtin_amdgcn_mfma_f32_16x16x32_bf16(
                        af[i], bfr[j], acc[i][j], 0, 0, 0);
        }
        __syncthreads();
    }
    #pragma unroll
    for (int i = 0; i < 4; ++i) {
        #pragma unroll
        for (int j = 0; j < 4; ++j) {
            long col = wn + j * 16 + fr;
            long rowb = m0 + wm + i * 16 + quad * 4;
            #pragma unroll
            for (int r = 0; r < 4; ++r)
                atomicAdd(&C[(rowb + r) * N + col], acc[i][j][r]);
        }
    }
}

// ---------------------------------------------------------------- block reduce helpers
__device__ __forceinline__ float block_max(float v, float* red, int lane, int wave) {
    #pragma unroll
    for (int o = 32; o; o >>= 1) v = fmaxf(v, __shfl_xor(v, o));
    if (lane == 0) red[wave] = v;
    __syncthreads();
    v = fmaxf(fmaxf(red[0], red[1]), fmaxf(red[2], red[3]));
    __syncthreads();
    return v;
}
__device__ __forceinline__ float block_sum(float v, float* red, int lane, int wave) {
    #pragma unroll
    for (int o = 32; o; o >>= 1) v += __shfl_xor(v, o);
    if (lane == 0) red[wave] = v;
    __syncthreads();
    v = red[0] + red[1] + red[2] + red[3];
    __syncthreads();
    return v;
}

// ---------------------------------------------------------------- fused softmax
// masked: e = where(A>0, dots, -inf); e[diag]=1.0; attn = softmax(e) -> attn_out
// if write_ds: also unmasked softmax of raw dots, written IN PLACE over dots
// (block-local: row fully read into registers before any write).
__global__ __launch_bounds__(256) void k_softmax_attn(
    float* __restrict__ dots, const float* __restrict__ Aadj,
    const unsigned long long* __restrict__ mask,
    float* __restrict__ attn_out, int write_ds)
{
    __shared__ float red[4];
    __shared__ unsigned long long msk[64];
    int row = blockIdx.x, tid = threadIdx.x;
    int lane = tid & 63, wave = tid >> 6;
    float* drow = dots + (long)row * 4096;
    if (mask) {
        if (tid < 64) msk[tid] = mask[(long)row * 64 + tid];
        __syncthreads();
    }
    float d[16], mv[16];
    float mmax = -1e30f, umax = -1e30f;
    #pragma unroll
    for (int i = 0; i < 16; ++i) {
        int j = tid + i * 256;
        float dv = drow[j];
        d[i] = dv;
        bool keep = mask ? ((msk[j >> 6] >> (j & 63)) & 1ull)
                         : (Aadj[(long)row * 4096 + j] > 0.f);
        float m = keep ? dv : -1e30f;
        if (j == row) m = 1.0f;
        mv[i] = m;
        mmax = fmaxf(mmax, m);
        umax = fmaxf(umax, dv);
    }
    float M1 = block_max(mmax, red, lane, wave);
    float s1 = 0.f;
    #pragma unroll
    for (int i = 0; i < 16; ++i) { float e = expf(mv[i] - M1); mv[i] = e; s1 += e; }
    s1 = block_sum(s1, red, lane, wave);
    float inv1 = 1.0f / s1;
    #pragma unroll
    for (int i = 0; i < 16; ++i)
        attn_out[(long)row * 4096 + tid + i * 256] = mv[i] * inv1;

    if (write_ds) {
        float M2 = block_max(umax, red, lane, wave);
        float s2 = 0.f;
        #pragma unroll
        for (int i = 0; i < 16; ++i) { float e = expf(d[i] - M2); d[i] = e; s2 += e; }
        s2 = block_sum(s2, red, lane, wave);
        float inv2 = 1.0f / s2;
        #pragma unroll
        for (int i = 0; i < 16; ++i)
            drow[tid + i * 256] = d[i] * inv2;
    }
}

// ---------------------------------------------------------------- x = xn + avcat(reindex) + bout
__global__ __launch_bounds__(256) void k_avres(
    const float* __restrict__ xn, const float* __restrict__ avcat,
    const float* __restrict__ bout, float* __restrict__ x)
{
    int idx = blockIdx.x * 256 + threadIdx.x;   // 524288
    int r = idx >> 6, c = idx & 63;
    int b = r >> 12, n = r & 4095;
    x[idx] = xn[idx] + avcat[(long)n * 128 + b * 64 + c] + bout[c];
}

// ---------------------------------------------------------------- MLP gemm, K=64, N=64 (fp32)
__global__ __launch_bounds__(256) void k_gemm64(
    const float* __restrict__ A, const float* __restrict__ W,
    const float* __restrict__ bias, const float* __restrict__ res,
    float* __restrict__ out, int act)
{
    __shared__ float As[64][65];
    __shared__ float Ws[64][65];
    int tid = threadIdx.x;
    int m0 = blockIdx.x * 64;
    #pragma unroll
    for (int it = 0; it < 16; ++it) {
        int idx = tid + it * 256;
        int r = idx >> 6, c = idx & 63;
        As[r][c] = A[(long)(m0 + r) * 64 + c];
        Ws[r][c] = W[(long)r * 64 + c];
    }
    __syncthreads();
    int tx = tid & 15, ty = tid >> 4;
    float acc[4][4] = {};
    #pragma unroll
    for (int k = 0; k < 64; ++k) {
        float a[4], w[4];
        #pragma unroll
        for (int i = 0; i < 4; ++i) a[i] = As[ty * 4 + i][k];
        #pragma unroll
        for (int j = 0; j < 4; ++j) w[j] = Ws[k][tx * 4 + j];
        #pragma unroll
        for (int i = 0; i < 4; ++i)
            #pragma unroll
            for (int j = 0; j < 4; ++j) acc[i][j] += a[i] * w[j];
    }
    #pragma unroll
    for (int i = 0; i < 4; ++i) {
        long row = m0 + ty * 4 + i;
        #pragma unroll
        for (int j = 0; j < 4; ++j) {
            int col = tx * 4 + j;
            float v = acc[i][j] + bias[col];
            if (act) v = gelu_exact(v);
            if (res) v += res[row * 64 + col];
            out[row * 64 + col] = v;
        }
    }
}

// ---------------------------------------------------------------- launch
extern "C" void kernel_launch(void* const* d_in, const int* in_sizes, int n_in,
                              void* d_out, int out_size, void* d_ws, size_t ws_size,
                              hipStream_t stream)
{
    const float* embed = (const float*)d_in[0];
    const float* Aadj  = (const float*)d_in[1];
    const float* g1    = (const float*)d_in[2];
    const float* b1    = (const float*)d_in[3];
    const float* Wqkv  = (const float*)d_in[4];
    const float* Wout  = (const float*)d_in[5];
    const float* bout  = (const float*)d_in[6];
    const float* g2    = (const float*)d_in[7];
    const float* b2    = (const float*)d_in[8];
    const float* W1    = (const float*)d_in[9];
    const float* bb1   = (const float*)d_in[10];
    const float* W2    = (const float*)d_in[11];
    const float* bb2   = (const float*)d_in[12];
    const float* gf    = (const float*)d_in[13];
    const float* bff   = (const float*)d_in[14];

    // output regions (fp32): [x 524288 | attn 16777216 | ds 16777216]
    float* ox    = (float*)d_out;            // final x; hosts avcat fp32 [4096,128] as scratch
    float* attnb = ox + 524288;              // [4096,4096] attn
    float* dsb   = attnb + 16777216;         // [4096,4096] raw dots -> ds (in place, l==1)

    if (ws_size < (10ull << 20)) {           // diagnostic guard (finite absmax => ws issue)
        k_zero<<<133120, 256, 0, stream>>>(ox, 34078720l);
        return;
    }

    // workspace: 9.02 MB (+2 MB mask if available)
    char* ws = (char*)d_ws;
    float*          x     = (float*)(ws + (0l << 20));            // 2 MB [8192,64]
    float*          xn    = (float*)(ws + (2l << 20));            // 2 MB xn / xm
    float*          h     = (float*)(ws + (4l << 20));            // 2 MB MLP hidden
    unsigned short* q     = (unsigned short*)(ws + (6l << 20));   // 1 MB [4096,256] bf16
    unsigned short* kmat  = (unsigned short*)(ws + (7l << 20));   // 1 MB [4096,256] bf16
    unsigned short* vwt   = (unsigned short*)(ws + (8l << 20));   // 1 MB [128,4096] bf16
    float*          Wfold = (float*)(ws + (9l << 20));            // 16 KB [64,64]
    unsigned long long* mask = (ws_size >= (12ull << 20))
        ? (unsigned long long*)(ws + (10l << 20)) : nullptr;      // 2 MB [4096,64]

    if (mask) k_maskpack<<<4096, 256, 0, stream>>>(Aadj, mask);

    for (int l = 0; l < 2; ++l) {
        const float* Wq = Wqkv + (long)l * 64 * 768;
        k_layernorm<<<2048, 256, 0, stream>>>(l ? x : embed, g1 + 64 * l, b1 + 64 * l, xn);
        k_wfold<<<16, 256, 0, stream>>>(Wq, Wout + (long)l * 256 * 64, Wfold);
        k_qk<<<dim3(64, 8), 256, 0, stream>>>(xn, Wq, q, kmat);
        k_xnw_t<<<dim3(64, 2), 256, 0, stream>>>(xn, Wfold, vwt);
        // dots = 0.125 * q @ k^T -> ds region (fp32)
        k_mfma_nt<<<dim3(32, 32), 256, 0, stream>>>(q, kmat, dsb, 4096, 256, 0.125f);
        // attn = masked softmax; l==1 also writes ds = unmasked softmax in place
        k_softmax_attn<<<4096, 256, 0, stream>>>(dsb, Aadj, mask, attnb, l == 1);
        // avcat = attn @ vWT^T via split-K atomics
        k_zero<<<2048, 256, 0, stream>>>(ox, 524288l);
        k_mfma_splitk<<<dim3(32, 8), 256, 0, stream>>>(attnb, vwt, ox);
        k_avres<<<2048, 256, 0, stream>>>(xn, ox, bout + 64 * l, x);
        k_layernorm<<<2048, 256, 0, stream>>>(x, g2 + 64 * l, b2 + 64 * l, xn);  // xm
        k_gemm64<<<128, 256, 0, stream>>>(xn, W1 + (long)l * 4096, bb1 + 64 * l,
                                          nullptr, h, 1);                 // h = gelu(...)
        k_gemm64<<<128, 256, 0, stream>>>(h, W2 + (long)l * 4096, bb2 + 64 * l,
                                          xn, x, 0);                      // x = xm + mlp
    }
    k_layernorm<<<2048, 256, 0, stream>>>(x, gf, bff, ox);   // final x (overwrites avcat)
}